// Round 1
// baseline (184.344 us; speedup 1.0000x reference)
//
#include <hip/hip_runtime.h>
#include <math.h>

#define NC 1024
#define NF 16384
#define NPTS (2*NF + 2*NC)   // 34816 packed points; same count of max-accumulators
#define TTGT 512             // targets staged in LDS per block (8 KB)
#define TPB  256
#define RQ   4               // query rows per thread

// Order-preserving float -> uint encoding (for atomicMax on floats incl. negatives)
__device__ __forceinline__ unsigned enc_f(float f) {
    unsigned u = __float_as_uint(f);
    return (u & 0x80000000u) ? ~u : (u | 0x80000000u);
}
__device__ __forceinline__ float dec_f(unsigned k) {
    unsigned u = (k & 0x80000000u) ? (k ^ 0x80000000u) : ~k;
    return __uint_as_float(u);
}

// Packed layout in ws (both pts and mm use the same indexing):
//   [0, NF)            : ref_points_f            (pass A queries; pass B/D targets)
//   [NF, 2NF)          : src_points_f transformed (pass B queries; pass A/C targets)
//   [2NF, 2NF+NC)      : ref_points_c            (pass C queries)
//   [2NF+NC, 2NF+2NC)  : src_points_c transformed (pass D queries)
__global__ __launch_bounds__(TPB) void prep_kernel(
    const float* __restrict__ refc, const float* __restrict__ srcc,
    const float* __restrict__ reff, const float* __restrict__ srcf,
    const float* __restrict__ T,
    float4* __restrict__ pts, unsigned* __restrict__ mm)
{
    int i = blockIdx.x * blockDim.x + threadIdx.x;
    if (i >= NPTS) return;
    mm[i] = 0u;  // less than any encoded float
    float x, y, z;
    bool xform;
    if (i < NF) {
        const float* p = reff + 3*i;             x=p[0]; y=p[1]; z=p[2]; xform=false;
    } else if (i < 2*NF) {
        const float* p = srcf + 3*(i - NF);      x=p[0]; y=p[1]; z=p[2]; xform=true;
    } else if (i < 2*NF + NC) {
        const float* p = refc + 3*(i - 2*NF);    x=p[0]; y=p[1]; z=p[2]; xform=false;
    } else {
        const float* p = srcc + 3*(i - 2*NF-NC); x=p[0]; y=p[1]; z=p[2]; xform=true;
    }
    if (xform) {
        float nx = T[0]*x + T[1]*y + T[2]*z  + T[3];
        float ny = T[4]*x + T[5]*y + T[6]*z  + T[7];
        float nz = T[8]*x + T[9]*y + T[10]*z + T[11];
        x = nx; y = ny; z = nz;
    }
    float h = 0.5f*(x*x + y*y + z*z);
    pts[i] = make_float4(x, y, z, h);
}

// For each query q: maxm[q] = max over targets p of (q.p - |p|^2/2).
// Then min_j ||q-p_j||^2 = |q|^2 - 2*maxm, and (min < thr^2) <=> maxm > |q|^2/2 - thr^2/2.
// Grid (1088 blocks) covers 4 passes:
//   A [0,512):     16 row-blocks x 32 chunks, Q=ref_f,     T=src_f_t
//   B [512,1024):  16 row-blocks x 32 chunks, Q=src_f_t,   T=ref_f
//   C [1024,1056):  1 row-block  x 32 chunks, Q=ref_c,     T=src_f_t
//   D [1056,1088):  1 row-block  x 32 chunks, Q=src_c_t,   T=ref_f
__global__ __launch_bounds__(TPB) void minmax_kernel(
    const float4* __restrict__ pts, unsigned* __restrict__ mm)
{
    __shared__ float4 sp[TTGT];
    int b = blockIdx.x;
    int qbase, tbase, rb, ck;
    if (b < 512)       { rb = b >> 5;              ck = b & 31;   qbase = 0;          tbase = NF; }
    else if (b < 1024) { int bb = b-512; rb = bb >> 5; ck = bb & 31; qbase = NF;      tbase = 0;  }
    else if (b < 1056) { rb = 0; ck = b - 1024;    qbase = 2*NF;      tbase = NF; }
    else               { rb = 0; ck = b - 1056;    qbase = 2*NF + NC; tbase = 0;  }

    int t = threadIdx.x;
    const float4* tp = pts + tbase + ck * TTGT;
    for (int s = t; s < TTGT; s += TPB) sp[s] = tp[s];

    int row0 = qbase + rb * (TPB * RQ) + t;
    float qx[RQ], qy[RQ], qz[RQ], acc[RQ];
#pragma unroll
    for (int r = 0; r < RQ; r++) {
        float4 q = pts[row0 + r * TPB];
        qx[r] = q.x; qy[r] = q.y; qz[r] = q.z;
        acc[r] = -3.0e38f;
    }
    __syncthreads();

#pragma unroll 8
    for (int j = 0; j < TTGT; j++) {
        float4 p = sp[j];   // wave-uniform address -> LDS broadcast, no conflicts
#pragma unroll
        for (int r = 0; r < RQ; r++) {
            float d = qx[r]*p.x + qy[r]*p.y + qz[r]*p.z - p.w;  // mul+fma+fma+sub
            acc[r] = fmaxf(acc[r], d);
        }
    }

#pragma unroll
    for (int r = 0; r < RQ; r++)
        atomicMax(&mm[row0 + r * TPB], enc_f(acc[r]));
}

// Block 0: n2p loss (2048 elems, thr=0.5). Block 1: p2p loss (32768 elems, thr=0.1).
// One pass: count positives, sum -log(p) over positives, -log1p(-p) over negatives.
// loss = (w_pos*S_pos + w_neg*S_neg)/N,  w_neg = cnt/N, w_pos = 1-w_neg.
__global__ __launch_bounds__(1024) void loss_kernel(
    const float4* __restrict__ pts, const unsigned* __restrict__ mm,
    const float* __restrict__ p2p_ref, const float* __restrict__ p2p_src,
    const float* __restrict__ n2p_ref, const float* __restrict__ n2p_src,
    float* __restrict__ out)
{
    __shared__ float rc[16], rp[16], rn[16];
    bool is_p2p = (blockIdx.x == 1);
    int N = is_p2p ? 2*NF : 2*NC;
    float thr_half = is_p2p ? 0.5f*(0.1f*0.1f) : 0.5f*(0.5f*0.5f);

    float cnt = 0.0f, spos = 0.0f, sneg = 0.0f;
    for (int i = threadIdx.x; i < N; i += 1024) {
        float score; int qi;
        if (is_p2p) {
            if (i < NF) { score = p2p_src[i];      qi = NF + i; }           // src_gt: pass B
            else        { score = p2p_ref[i - NF]; qi = i - NF; }           // ref_gt: pass A
        } else {
            if (i < NC) { score = n2p_src[i];      qi = 2*NF + NC + i; }    // src_gt_n: pass D
            else        { score = n2p_ref[i - NC]; qi = 2*NF + (i - NC); }  // ref_gt_n: pass C
        }
        float maxm = dec_f(mm[qi]);
        float hq = pts[qi].w;          // |q|^2 / 2
        bool g = maxm > (hq - thr_half);
        if (g) { cnt += 1.0f; spos -= logf(score); }
        else   { sneg -= log1pf(-score); }
    }

    int lane = threadIdx.x & 63, wid = threadIdx.x >> 6;
#pragma unroll
    for (int off = 32; off > 0; off >>= 1) {
        cnt  += __shfl_down(cnt,  off, 64);
        spos += __shfl_down(spos, off, 64);
        sneg += __shfl_down(sneg, off, 64);
    }
    if (lane == 0) { rc[wid] = cnt; rp[wid] = spos; rn[wid] = sneg; }
    __syncthreads();
    if (threadIdx.x == 0) {
        float c = 0, sp = 0, sn = 0;
        for (int w = 0; w < 16; w++) { c += rc[w]; sp += rp[w]; sn += rn[w]; }
        float wneg = c / (float)N;
        float wpos = 1.0f - wneg;
        out[blockIdx.x] = (wpos * sp + wneg * sn) / (float)N;   // out[0]=n2p, out[1]=p2p
    }
}

extern "C" void kernel_launch(void* const* d_in, const int* in_sizes, int n_in,
                              void* d_out, int out_size, void* d_ws, size_t ws_size,
                              hipStream_t stream) {
    (void)in_sizes; (void)n_in; (void)out_size; (void)ws_size;
    const float* refc = (const float*)d_in[0];   // ref_points_c  [1024,3]
    const float* srcc = (const float*)d_in[1];   // src_points_c  [1024,3]
    const float* reff = (const float*)d_in[2];   // ref_points_f  [16384,3]
    const float* srcf = (const float*)d_in[3];   // src_points_f  [16384,3]
    const float* T    = (const float*)d_in[4];   // transform [4,4]
    const float* p2p_ref = (const float*)d_in[5];
    const float* p2p_src = (const float*)d_in[6];
    const float* n2p_ref = (const float*)d_in[7];
    const float* n2p_src = (const float*)d_in[8];
    float* out = (float*)d_out;

    float4*   pts = (float4*)d_ws;
    unsigned* mm  = (unsigned*)((char*)d_ws + (size_t)NPTS * sizeof(float4));

    prep_kernel<<<(NPTS + TPB - 1) / TPB, TPB, 0, stream>>>(refc, srcc, reff, srcf, T, pts, mm);
    minmax_kernel<<<1088, TPB, 0, stream>>>(pts, mm);
    loss_kernel<<<2, 1024, 0, stream>>>(pts, mm, p2p_ref, p2p_src, n2p_ref, n2p_src, out);
}

// Round 2
// 147.259 us; speedup vs baseline: 1.2518x; 1.2518x over previous
//
#include <hip/hip_runtime.h>
#include <math.h>

#define NC 1024
#define NF 16384
#define NPTS (2*NF + 2*NC)   // 34816 packed points / max-accumulators
#define TPB  256

typedef _Float16 f16x8 __attribute__((ext_vector_type(8)));
typedef float    f32x16 __attribute__((ext_vector_type(16)));

// Order-preserving float -> uint encoding (for atomicMax on floats incl. negatives)
__device__ __forceinline__ unsigned enc_f(float f) {
    unsigned u = __float_as_uint(f);
    return (u & 0x80000000u) ? ~u : (u | 0x80000000u);
}
__device__ __forceinline__ float dec_f(unsigned k) {
    unsigned u = (k & 0x80000000u) ? (k ^ 0x80000000u) : ~k;
    return __uint_as_float(u);
}

// Packed point-index layout (recs, hq, mm all share it):
//   [0, NF)            : ref_points_f             (pass A queries; pass B/D targets)
//   [NF, 2NF)          : src_points_f transformed (pass B queries; pass A/C targets)
//   [2NF, 2NF+NC)      : ref_points_c             (pass C queries)
//   [2NF+NC, 2NF+2NC)  : src_points_c transformed (pass D queries)
//
// f16 hi/lo split records for MFMA K-packing (K=16, k14/k15 zero):
//   A rec: k = [qhx qhy qhz | qlx qly qlz | qhx qhy qhz | 1 1 | qlx qly qlz | 0 0]
//   B rec: k = [phx phy phz | phx phy phz | plx ply plz | -hh -hl | plx ply plz | 0 0]
// => sum_k A[k]B[k] = (qh+ql).(ph+pl) - h_p  (residual ~1e-5)
__global__ __launch_bounds__(TPB) void prep_kernel(
    const float* __restrict__ refc, const float* __restrict__ srcc,
    const float* __restrict__ reff, const float* __restrict__ srcf,
    const float* __restrict__ T,
    f16x8* __restrict__ a0, f16x8* __restrict__ a1,
    f16x8* __restrict__ b0, f16x8* __restrict__ b1,
    float* __restrict__ hqv, unsigned* __restrict__ mm)
{
    int i = blockIdx.x * blockDim.x + threadIdx.x;
    if (i >= NPTS) return;
    mm[i] = 0u;  // below every encoded float
    float x, y, z;
    bool xform;
    if (i < NF) {
        const float* p = reff + 3*i;             x=p[0]; y=p[1]; z=p[2]; xform=false;
    } else if (i < 2*NF) {
        const float* p = srcf + 3*(i - NF);      x=p[0]; y=p[1]; z=p[2]; xform=true;
    } else if (i < 2*NF + NC) {
        const float* p = refc + 3*(i - 2*NF);    x=p[0]; y=p[1]; z=p[2]; xform=false;
    } else {
        const float* p = srcc + 3*(i - 2*NF-NC); x=p[0]; y=p[1]; z=p[2]; xform=true;
    }
    if (xform) {
        float nx = T[0]*x + T[1]*y + T[2]*z  + T[3];
        float ny = T[4]*x + T[5]*y + T[6]*z  + T[7];
        float nz = T[8]*x + T[9]*y + T[10]*z + T[11];
        x = nx; y = ny; z = nz;
    }
    float h = 0.5f*(x*x + y*y + z*z);
    hqv[i] = h;
    _Float16 hx = (_Float16)x; _Float16 hy = (_Float16)y; _Float16 hz = (_Float16)z;
    _Float16 lx = (_Float16)(x - (float)hx);
    _Float16 ly = (_Float16)(y - (float)hy);
    _Float16 lz = (_Float16)(z - (float)hz);
    _Float16 hh = (_Float16)h;
    _Float16 hl = (_Float16)(h - (float)hh);
    _Float16 one = (_Float16)1.0f, zz = (_Float16)0.0f;
    a0[i] = (f16x8){hx, hy, hz, lx, ly, lz, hx, hy};
    a1[i] = (f16x8){hz, one, one, lx, ly, lz, zz, zz};
    b0[i] = (f16x8){hx, hy, hz, hx, hy, hz, lx, ly};
    b1[i] = (f16x8){lz, (_Float16)(-hh), (_Float16)(-hl), lx, ly, lz, zz, zz};
}

// MFMA min-distance kernel. Each block: 256 query rows x 1024 targets.
// Wave w handles rows [w*64, w*64+64) as two 32-row MFMA A-tiles; targets
// staged in LDS as two K-group planes of f16x8 records.
// Grid 2176 blocks:
//   A [0,1024):     rb in [0,64) x ck in [0,16)   Q=ref_f    T=src_f_t
//   B [1024,2048):  same shape                     Q=src_f_t  T=ref_f
//   C [2048,2112):  rb in [0,4)  x ck in [0,16)   Q=ref_c    T=src_f_t
//   D [2112,2176):  same shape                     Q=src_c_t  T=ref_f
__global__ __launch_bounds__(TPB) void minmax_kernel(
    const f16x8* __restrict__ a0g, const f16x8* __restrict__ a1g,
    const f16x8* __restrict__ b0g, const f16x8* __restrict__ b1g,
    unsigned* __restrict__ mm)
{
    // 32KB target planes, reused as 4x8704B per-wave reduce scratch (34816B total)
    __shared__ __align__(16) char ldsraw[34816];
    f16x8* sbuf = (f16x8*)ldsraw;

    int b = blockIdx.x;
    int qoff, toff, rb, ck;
    if (b < 1024)      { rb = b >> 4;               ck = b & 15; qoff = 0;          toff = NF; }
    else if (b < 2048) { int bb = b-1024; rb = bb>>4; ck = bb&15; qoff = NF;        toff = 0;  }
    else if (b < 2112) { int bb = b-2048; rb = bb>>4; ck = bb&15; qoff = 2*NF;      toff = NF; }
    else               { int bb = b-2112; rb = bb>>4; ck = bb&15; qoff = 2*NF + NC; toff = 0;  }
    int rbase = qoff + rb * 256;
    int tbase = toff + ck * 1024;

    int tid = threadIdx.x, wv = tid >> 6, ln = tid & 63;

    // stage: plane0 = b0 records, plane1 = b1 records (16B each, coalesced)
#pragma unroll
    for (int k = 0; k < 8; k++) {
        int i = tid + k * 256;
        sbuf[i] = (i < 1024) ? b0g[tbase + i] : b1g[tbase + i - 1024];
    }

    int m  = ln & 31;        // A-row within tile / B-col (target) within tile
    int hf = ln >> 5;        // K-group select
    int rA = rbase + wv * 64 + m;
    f16x8 aA = hf ? a1g[rA]      : a0g[rA];        // rows [wv*64, wv*64+32)
    f16x8 aB = hf ? a1g[rA + 32] : a0g[rA + 32];   // rows [wv*64+32, wv*64+64)

    f32x16 accA, accB;
#pragma unroll
    for (int r = 0; r < 16; r++) { accA[r] = -3.0e38f; accB[r] = -3.0e38f; }
    f32x16 zf = {};

    __syncthreads();

    int sb0 = hf * 1024 + m;
#pragma unroll 2
    for (int tp = 0; tp < 16; ++tp) {              // 2 target-tiles (64 targets) per iter
        f16x8 bA = sbuf[sb0 + tp * 64];
        f16x8 bB = sbuf[sb0 + tp * 64 + 32];
        f32x16 d0 = __builtin_amdgcn_mfma_f32_32x32x16_f16(aA, bA, zf, 0, 0, 0);
        f32x16 d1 = __builtin_amdgcn_mfma_f32_32x32x16_f16(aA, bB, zf, 0, 0, 0);
#pragma unroll
        for (int r = 0; r < 16; r++) accA[r] = fmaxf(accA[r], fmaxf(d0[r], d1[r]));
        f32x16 d2 = __builtin_amdgcn_mfma_f32_32x32x16_f16(aB, bA, zf, 0, 0, 0);
        f32x16 d3 = __builtin_amdgcn_mfma_f32_32x32x16_f16(aB, bB, zf, 0, 0, 0);
#pragma unroll
        for (int r = 0; r < 16; r++) accB[r] = fmaxf(accB[r], fmaxf(d2[r], d3[r]));
    }

    __syncthreads();   // everyone done reading sbuf before scratch overwrite

    // Col-reduce via LDS transpose. C/D layout: col=lane&31, row=(reg&3)+8*(reg>>2)+4*(lane>>5).
    // Scratch row stride 34 floats (136B): write banks 2-way (free), read via float2.
    float* scr = (float*)(ldsraw + wv * 8704);
#pragma unroll
    for (int r = 0; r < 16; r++) {
        int rowA = (r & 3) + 8 * (r >> 2) + 4 * hf;
        scr[rowA * 34 + m]        = accA[r];
        scr[(rowA + 32) * 34 + m] = accB[r];
    }
    __syncthreads();   // drain LDS writes (lgkmcnt) before cross-lane reads

    float mx = -3.0e38f;
#pragma unroll
    for (int k = 0; k < 16; k++) {
        float2 v = *(float2*)(ldsraw + wv * 8704 + ln * 136 + k * 8);
        mx = fmaxf(mx, fmaxf(v.x, v.y));
    }
    atomicMax(&mm[rbase + wv * 64 + ln], enc_f(mx));
}

// Block 0: n2p loss (2048 elems, thr=0.5). Block 1: p2p loss (32768 elems, thr=0.1).
__global__ __launch_bounds__(1024) void loss_kernel(
    const float* __restrict__ hqv, const unsigned* __restrict__ mm,
    const float* __restrict__ p2p_ref, const float* __restrict__ p2p_src,
    const float* __restrict__ n2p_ref, const float* __restrict__ n2p_src,
    float* __restrict__ out)
{
    __shared__ float rc[16], rp[16], rn[16];
    bool is_p2p = (blockIdx.x == 1);
    int N = is_p2p ? 2*NF : 2*NC;
    float thr_half = is_p2p ? 0.5f*(0.1f*0.1f) : 0.5f*(0.5f*0.5f);

    float cnt = 0.0f, spos = 0.0f, sneg = 0.0f;
    for (int i = threadIdx.x; i < N; i += 1024) {
        float score; int qi;
        if (is_p2p) {
            if (i < NF) { score = p2p_src[i];      qi = NF + i; }           // src_gt: pass B
            else        { score = p2p_ref[i - NF]; qi = i - NF; }           // ref_gt: pass A
        } else {
            if (i < NC) { score = n2p_src[i];      qi = 2*NF + NC + i; }    // src_gt_n: pass D
            else        { score = n2p_ref[i - NC]; qi = 2*NF + (i - NC); }  // ref_gt_n: pass C
        }
        float maxm = dec_f(mm[qi]);
        float hq = hqv[qi];            // |q|^2 / 2 (fp32 exact)
        bool g = maxm > (hq - thr_half);
        if (g) { cnt += 1.0f; spos -= logf(score); }
        else   { sneg -= log1pf(-score); }
    }

    int lane = threadIdx.x & 63, wid = threadIdx.x >> 6;
#pragma unroll
    for (int off = 32; off > 0; off >>= 1) {
        cnt  += __shfl_down(cnt,  off, 64);
        spos += __shfl_down(spos, off, 64);
        sneg += __shfl_down(sneg, off, 64);
    }
    if (lane == 0) { rc[wid] = cnt; rp[wid] = spos; rn[wid] = sneg; }
    __syncthreads();
    if (threadIdx.x == 0) {
        float c = 0, sp = 0, sn = 0;
        for (int w = 0; w < 16; w++) { c += rc[w]; sp += rp[w]; sn += rn[w]; }
        float wneg = c / (float)N;
        float wpos = 1.0f - wneg;
        out[blockIdx.x] = (wpos * sp + wneg * sn) / (float)N;   // out[0]=n2p, out[1]=p2p
    }
}

extern "C" void kernel_launch(void* const* d_in, const int* in_sizes, int n_in,
                              void* d_out, int out_size, void* d_ws, size_t ws_size,
                              hipStream_t stream) {
    (void)in_sizes; (void)n_in; (void)out_size; (void)ws_size;
    const float* refc = (const float*)d_in[0];
    const float* srcc = (const float*)d_in[1];
    const float* reff = (const float*)d_in[2];
    const float* srcf = (const float*)d_in[3];
    const float* T    = (const float*)d_in[4];
    const float* p2p_ref = (const float*)d_in[5];
    const float* p2p_src = (const float*)d_in[6];
    const float* n2p_ref = (const float*)d_in[7];
    const float* n2p_src = (const float*)d_in[8];
    float* out = (float*)d_out;

    f16x8* a0 = (f16x8*)d_ws;
    f16x8* a1 = a0 + NPTS;
    f16x8* b0 = a1 + NPTS;
    f16x8* b1 = b0 + NPTS;
    float* hqv = (float*)(b1 + NPTS);
    unsigned* mm = (unsigned*)(hqv + NPTS);   // total ws use: 72*NPTS = ~2.5 MB

    prep_kernel<<<(NPTS + TPB - 1) / TPB, TPB, 0, stream>>>(
        refc, srcc, reff, srcf, T, a0, a1, b0, b1, hqv, mm);
    minmax_kernel<<<2176, TPB, 0, stream>>>(a0, a1, b0, b1, mm);
    loss_kernel<<<2, 1024, 0, stream>>>(hqv, mm, p2p_ref, p2p_src, n2p_ref, n2p_src, out);
}

// Round 3
// 126.790 us; speedup vs baseline: 1.4539x; 1.1614x over previous
//
#include <hip/hip_runtime.h>
#include <math.h>

#define NC 1024
#define NF 16384
#define NPTS (2*NF + 2*NC)   // 34816 packed points / max-accumulators
#define TPB  256

typedef _Float16 f16x8 __attribute__((ext_vector_type(8)));
typedef float    f32x16 __attribute__((ext_vector_type(16)));

// Order-preserving float -> uint encoding (for atomicMax on floats incl. negatives)
__device__ __forceinline__ unsigned enc_f(float f) {
    unsigned u = __float_as_uint(f);
    return (u & 0x80000000u) ? ~u : (u | 0x80000000u);
}
__device__ __forceinline__ float dec_f(unsigned k) {
    unsigned u = (k & 0x80000000u) ? (k ^ 0x80000000u) : ~k;
    return __uint_as_float(u);
}

// Packed point-index layout (recs, hq, mm all share it):
//   [0, NF)            : ref_points_f             (pass A queries; pass B/D targets)
//   [NF, 2NF)          : src_points_f transformed (pass B queries; pass A/C targets)
//   [2NF, 2NF+NC)      : ref_points_c             (pass C queries)
//   [2NF+NC, 2NF+2NC)  : src_points_c transformed (pass D queries)
//
// f16 hi/lo split records for MFMA K-packing (K=16):
//   A rec: k = [qhx qhy qhz | qlx qly qlz | qhx qhy qhz | 1 1 | qlx qly qlz | 0 0]
//   B rec: k = [phx phy phz | phx phy phz | plx ply plz | -hh -hl | plx ply plz | 0 0]
// => sum_k A[k]B[k] = (qh+ql).(ph+pl) - h_p  (residual ~1e-5); verified absmax 0 in R2.
__global__ __launch_bounds__(TPB) void prep_kernel(
    const float* __restrict__ refc, const float* __restrict__ srcc,
    const float* __restrict__ reff, const float* __restrict__ srcf,
    const float* __restrict__ T,
    f16x8* __restrict__ a0, f16x8* __restrict__ a1,
    f16x8* __restrict__ b0, f16x8* __restrict__ b1,
    float* __restrict__ hqv, unsigned* __restrict__ mm)
{
    int i = blockIdx.x * blockDim.x + threadIdx.x;
    if (i >= NPTS) return;
    mm[i] = 0u;  // below every encoded float
    float x, y, z;
    bool xform;
    if (i < NF) {
        const float* p = reff + 3*i;             x=p[0]; y=p[1]; z=p[2]; xform=false;
    } else if (i < 2*NF) {
        const float* p = srcf + 3*(i - NF);      x=p[0]; y=p[1]; z=p[2]; xform=true;
    } else if (i < 2*NF + NC) {
        const float* p = refc + 3*(i - 2*NF);    x=p[0]; y=p[1]; z=p[2]; xform=false;
    } else {
        const float* p = srcc + 3*(i - 2*NF-NC); x=p[0]; y=p[1]; z=p[2]; xform=true;
    }
    if (xform) {
        float nx = T[0]*x + T[1]*y + T[2]*z  + T[3];
        float ny = T[4]*x + T[5]*y + T[6]*z  + T[7];
        float nz = T[8]*x + T[9]*y + T[10]*z + T[11];
        x = nx; y = ny; z = nz;
    }
    float h = 0.5f*(x*x + y*y + z*z);
    hqv[i] = h;
    _Float16 hx = (_Float16)x; _Float16 hy = (_Float16)y; _Float16 hz = (_Float16)z;
    _Float16 lx = (_Float16)(x - (float)hx);
    _Float16 ly = (_Float16)(y - (float)hy);
    _Float16 lz = (_Float16)(z - (float)hz);
    _Float16 hh = (_Float16)h;
    _Float16 hl = (_Float16)(h - (float)hh);
    _Float16 one = (_Float16)1.0f, zz = (_Float16)0.0f;
    a0[i] = (f16x8){hx, hy, hz, lx, ly, lz, hx, hy};
    a1[i] = (f16x8){hz, one, one, lx, ly, lz, zz, zz};
    b0[i] = (f16x8){hx, hy, hz, hx, hy, hz, lx, ly};
    b1[i] = (f16x8){lz, (_Float16)(-hh), (_Float16)(-hl), lx, ly, lz, zz, zz};
}

// MFMA min-distance kernel. Block: 128 query rows x 1024 targets; wave w owns
// rows [w*32, w*32+32) as ONE 32-row A-tile (16-reg acc -> fits arch VGPRs,
// no accvgpr shuffling; R2's 64-rows/wave variant went AGPR-bound at VGPR=60).
// Grid 4352:
//   A [0,2048):     rb in [0,128) x ck in [0,16)  Q=ref_f    T=src_f_t
//   B [2048,4096):  same shape                     Q=src_f_t  T=ref_f
//   C [4096,4224):  rb in [0,8)   x ck in [0,16)  Q=ref_c    T=src_f_t
//   D [4224,4352):  same shape                     Q=src_c_t  T=ref_f
__global__ __launch_bounds__(TPB, 2) void minmax_kernel(
    const f16x8* __restrict__ a0g, const f16x8* __restrict__ a1g,
    const f16x8* __restrict__ b0g, const f16x8* __restrict__ b1g,
    unsigned* __restrict__ mm)
{
    // 32KB target planes; tail 18.4KB reused as 4x4608B per-wave reduce scratch
    __shared__ __align__(16) char ldsraw[32768];
    f16x8* sbuf = (f16x8*)ldsraw;

    int b = blockIdx.x;
    int qoff, toff, rb, ck;
    if (b < 2048)      { rb = b >> 4;                ck = b & 15;  qoff = 0;          toff = NF; }
    else if (b < 4096) { int bb=b-2048; rb=bb>>4;    ck=bb&15;     qoff = NF;         toff = 0;  }
    else if (b < 4224) { int bb=b-4096; rb=bb>>4;    ck=bb&15;     qoff = 2*NF;       toff = NF; }
    else               { int bb=b-4224; rb=bb>>4;    ck=bb&15;     qoff = 2*NF + NC;  toff = 0;  }
    int rbase = qoff + rb * 128;
    int tbase = toff + ck * 1024;

    int tid = threadIdx.x, wv = tid >> 6, ln = tid & 63;

    // stage: plane0 = b0 records, plane1 = b1 records (16B/lane, coalesced)
#pragma unroll
    for (int k = 0; k < 8; k++) {
        int i = tid + k * 256;
        sbuf[i] = (i < 1024) ? b0g[tbase + i] : b1g[tbase + i - 1024];
    }

    int m  = ln & 31;        // A-row within tile / B-col (target) within tile
    int hf = ln >> 5;        // K-group select
    int rA = rbase + wv * 32 + m;
    f16x8 aA = hf ? a1g[rA] : a0g[rA];

    f32x16 acc;
#pragma unroll
    for (int r = 0; r < 16; r++) acc[r] = -3.0e38f;
    f32x16 zf = {};

    __syncthreads();

    int sidx = hf * 1024 + m;
#pragma unroll
    for (int tp = 0; tp < 16; ++tp) {              // 2 target-tiles (64 targets)/iter
        f16x8 bA = sbuf[sidx + tp * 64];
        f16x8 bB = sbuf[sidx + tp * 64 + 32];
        f32x16 d0 = __builtin_amdgcn_mfma_f32_32x32x16_f16(aA, bA, zf, 0, 0, 0);
        f32x16 d1 = __builtin_amdgcn_mfma_f32_32x32x16_f16(aA, bB, zf, 0, 0, 0);
#pragma unroll
        for (int r = 0; r < 16; r++)
            acc[r] = fmaxf(fmaxf(acc[r], d0[r]), d1[r]);   // -> v_max3_f32
    }

    __syncthreads();   // all waves done reading sbuf before scratch overwrite

    // Col-reduce via LDS transpose. C/D layout: col=lane&31, row=(r&3)+8*(r>>2)+4*hf.
    // Scratch row stride 36 floats (144B, 16B-aligned): write conflicts 2-way (free).
    float* scr = (float*)(ldsraw + wv * 4608);     // 32 rows x 36 floats
#pragma unroll
    for (int r = 0; r < 16; r++) {
        int row = (r & 3) + 8 * (r >> 2) + 4 * hf;
        scr[row * 36 + m] = acc[r];
    }
    __syncthreads();   // drain LDS writes before cross-lane reads

    const float4* rv = (const float4*)(ldsraw + wv * 4608 + (ln & 31) * 144 + (ln >> 5) * 64);
    float mx = -3.0e38f;
#pragma unroll
    for (int k = 0; k < 4; k++) {
        float4 v = rv[k];
        mx = fmaxf(fmaxf(mx, fmaxf(v.x, v.y)), fmaxf(v.z, v.w));
    }
    mx = fmaxf(mx, __shfl_down(mx, 32, 64));
    if (ln < 32) atomicMax(&mm[rbase + wv * 32 + ln], enc_f(mx));
}

// Block 0: n2p loss (2048 elems, thr=0.5). Block 1: p2p loss (32768 elems, thr=0.1).
__global__ __launch_bounds__(1024) void loss_kernel(
    const float* __restrict__ hqv, const unsigned* __restrict__ mm,
    const float* __restrict__ p2p_ref, const float* __restrict__ p2p_src,
    const float* __restrict__ n2p_ref, const float* __restrict__ n2p_src,
    float* __restrict__ out)
{
    __shared__ float rc[16], rp[16], rn[16];
    bool is_p2p = (blockIdx.x == 1);
    int N = is_p2p ? 2*NF : 2*NC;
    float thr_half = is_p2p ? 0.5f*(0.1f*0.1f) : 0.5f*(0.5f*0.5f);

    float cnt = 0.0f, spos = 0.0f, sneg = 0.0f;
    for (int i = threadIdx.x; i < N; i += 1024) {
        float score; int qi;
        if (is_p2p) {
            if (i < NF) { score = p2p_src[i];      qi = NF + i; }           // src_gt: pass B
            else        { score = p2p_ref[i - NF]; qi = i - NF; }           // ref_gt: pass A
        } else {
            if (i < NC) { score = n2p_src[i];      qi = 2*NF + NC + i; }    // src_gt_n: pass D
            else        { score = n2p_ref[i - NC]; qi = 2*NF + (i - NC); }  // ref_gt_n: pass C
        }
        float maxm = dec_f(mm[qi]);
        float hq = hqv[qi];            // |q|^2 / 2 (fp32 exact)
        bool g = maxm > (hq - thr_half);
        if (g) { cnt += 1.0f; spos -= logf(score); }
        else   { sneg -= log1pf(-score); }
    }

    int lane = threadIdx.x & 63, wid = threadIdx.x >> 6;
#pragma unroll
    for (int off = 32; off > 0; off >>= 1) {
        cnt  += __shfl_down(cnt,  off, 64);
        spos += __shfl_down(spos, off, 64);
        sneg += __shfl_down(sneg, off, 64);
    }
    if (lane == 0) { rc[wid] = cnt; rp[wid] = spos; rn[wid] = sneg; }
    __syncthreads();
    if (threadIdx.x == 0) {
        float c = 0, sp = 0, sn = 0;
        for (int w = 0; w < 16; w++) { c += rc[w]; sp += rp[w]; sn += rn[w]; }
        float wneg = c / (float)N;
        float wpos = 1.0f - wneg;
        out[blockIdx.x] = (wpos * sp + wneg * sn) / (float)N;   // out[0]=n2p, out[1]=p2p
    }
}

extern "C" void kernel_launch(void* const* d_in, const int* in_sizes, int n_in,
                              void* d_out, int out_size, void* d_ws, size_t ws_size,
                              hipStream_t stream) {
    (void)in_sizes; (void)n_in; (void)out_size; (void)ws_size;
    const float* refc = (const float*)d_in[0];
    const float* srcc = (const float*)d_in[1];
    const float* reff = (const float*)d_in[2];
    const float* srcf = (const float*)d_in[3];
    const float* T    = (const float*)d_in[4];
    const float* p2p_ref = (const float*)d_in[5];
    const float* p2p_src = (const float*)d_in[6];
    const float* n2p_ref = (const float*)d_in[7];
    const float* n2p_src = (const float*)d_in[8];
    float* out = (float*)d_out;

    f16x8* a0 = (f16x8*)d_ws;
    f16x8* a1 = a0 + NPTS;
    f16x8* b0 = a1 + NPTS;
    f16x8* b1 = b0 + NPTS;
    float* hqv = (float*)(b1 + NPTS);
    unsigned* mm = (unsigned*)(hqv + NPTS);   // total ws use: 72*NPTS = ~2.5 MB

    prep_kernel<<<(NPTS + TPB - 1) / TPB, TPB, 0, stream>>>(
        refc, srcc, reff, srcf, T, a0, a1, b0, b1, hqv, mm);
    minmax_kernel<<<4352, TPB, 0, stream>>>(a0, a1, b0, b1, mm);
    loss_kernel<<<2, 1024, 0, stream>>>(hqv, mm, p2p_ref, p2p_src, n2p_ref, n2p_src, out);
}